// Round 3
// baseline (2043.773 us; speedup 1.0000x reference)
//
#include <hip/hip_runtime.h>
#include <hip/hip_bf16.h>
#include <stdint.h>

#define NB 16
#define NPTS 4096
#define NS 1024
#define NK 32
#define NT_COLS (NB*NS*NK)   // 524288 columns (b*NS+s)*NK + k
#define NBUCK 64             // stat-accumulator buckets

typedef __hip_bfloat16 bf16;
typedef __attribute__((ext_vector_type(8))) short short8;   // 8 bf16 (4 VGPRs)
typedef __attribute__((ext_vector_type(4))) float floatx4;  // MFMA C/D
typedef __attribute__((ext_vector_type(2))) float f32x2;    // pk-fp32 pair

__device__ __forceinline__ unsigned short f2bf_bits(float v) {
  bf16 b = __float2bfloat16(v);
  return *(unsigned short*)&b;
}

// DPP-shifted fmax (verified gfx950 R5/R7/R8). Inactive/OOB src lanes keep old=x.
template<int CTRL, int RM, int BM>
__device__ __forceinline__ float fmax_dpp(float x) {
  int o = __builtin_amdgcn_update_dpp(__float_as_int(x), __float_as_int(x),
                                      CTRL, RM, BM, false);
  return fmaxf(x, __int_as_float(o));
}
// DPP add with zero-fill identity; RM-masked rows add 0 (old=0).
template<int CTRL, int RM>
__device__ __forceinline__ float add_dpp(float x) {
  int o = __builtin_amdgcn_update_dpp(0, __float_as_int(x), CTRL, RM, 0xF, true);
  return __fadd_rn(x, __int_as_float(o));
}
// 16-lane row sum -> lane 15 of each row (mfma C-layout stats).
__device__ __forceinline__ float add16_dpp(float x) {
  x = add_dpp<0x111,0xF>(x); x = add_dpp<0x112,0xF>(x);
  x = add_dpp<0x114,0xF>(x); x = add_dpp<0x118,0xF>(x);
  return x;
}
// full wave64 sum -> lane 63.
__device__ __forceinline__ float add64_dpp(float x) {
  x = add_dpp<0x111,0xF>(x); x = add_dpp<0x112,0xF>(x);
  x = add_dpp<0x114,0xF>(x); x = add_dpp<0x118,0xF>(x);
  x = add_dpp<0x142,0xA>(x);   // row_bcast:15 -> rows 1,3
  x = add_dpp<0x143,0xC>(x);   // row_bcast:31 -> rows 2,3
  return x;
}

// ---------------- FPS: 4 independent batches per block (latency hiding) -----
// R17 post-mortems: R15 (512 thr, SAME batch) regressed — lockstepped waves
// can't hide each other's chain stalls. R16 (tree argmax) regressed — with
// 1 wave/SIMD every extra inst costs ~4-8cy latency, and the serial argmax
// chain was already hidden under the dist-loop ILP. Conclusion: k_fps is a
// ~1300cy/iter LATENCY CHAIN; the fix is waves from INDEPENDENT batches on
// each SIMD. This kernel: 4 batches/block (16 waves, 4/SIMD). Per batch the
// structure is EXACTLY the proven R14 one (4 waves x 64 lanes x 16 pts).
// LDS point arrays + xs[cur] broadcast are eliminated: the argmax tracks the
// winning point's COORDS (bit-copies) instead of its index; the wave
// candidate is float4(M, x,y,z); the cross-wave scan yields next-center
// coords directly. Selection is bit-identical: exact-rn dist (contract off,
// no FMA, x+(-c)==x-c), in-lane ascending strict > (nd0 before nd1), in-wave
// ctz(ballot), cross-wave ascending strict > over 4 wave candidates.
__global__ __launch_bounds__(1024) void k_fps(const float* __restrict__ xyz,
                                              float* __restrict__ newxyz,
                                              float* __restrict__ out0,
                                              float* __restrict__ zero_region) {
  const int t = threadIdx.x;
  {
    float* zp = zero_region + (size_t)blockIdx.x*8192 + t;
    #pragma unroll
    for (int j = 0; j < 8; ++j) zp[j*1024] = 0.f;
  }
  const int half = t >> 8;               // 0..3  : which batch in this block
  const int tl   = t & 255;              // thread-in-batch (matches R14's t)
  const int b    = blockIdx.x*4 + half;
  const int lane = t & 63;               // == tl & 63 (halves are 256-aligned)
  const int wv4  = tl >> 6;              // wave-in-batch 0..3
  __shared__ __align__(16) float4 pair[2][4][4];  // [dbuf][half][wave]
  const float* p = xyz + (size_t)b * 3 * NPTS;

  // points -> registers (64B contiguous per lane per coord; wave covers 4KB)
  f32x2 px[8], py[8], pz[8];
  float dist[16];
  const int p0 = tl * 16;
  {
    const float4* xp = (const float4*)(p + p0);
    const float4* yp = (const float4*)(p + NPTS + p0);
    const float4* zp4 = (const float4*)(p + 2*NPTS + p0);
    #pragma unroll
    for (int q = 0; q < 4; ++q) {
      float4 ax = xp[q], ay = yp[q], az = zp4[q];
      px[2*q]   = (f32x2){ax.x, ax.y};  px[2*q+1] = (f32x2){ax.z, ax.w};
      py[2*q]   = (f32x2){ay.x, ay.y};  py[2*q+1] = (f32x2){ay.z, ay.w};
      pz[2*q]   = (f32x2){az.x, az.y};  pz[2*q+1] = (f32x2){az.z, az.w};
    }
    #pragma unroll
    for (int j = 0; j < 16; ++j) dist[j] = 1e10f;
  }
  // first center = point 0 of this batch (broadcast global loads, L2-hit)
  float cx = p[0], cy = p[NPTS], cz = p[2*NPTS];

  for (int i = 0; i < NS; ++i) {
    if (tl == 0) {
      size_t q = (size_t)b*3*NS + i;
      out0[q] = cx; out0[q + NS] = cy; out0[q + 2*NS] = cz;  // bit-exact
      size_t o = (size_t)(b*NS + i)*3;
      newxyz[o] = cx; newxyz[o+1] = cy; newxyz[o+2] = cz;
    }
    if (i == NS-1) break;
    const f32x2 ncx = (f32x2){-cx, -cx};   // exact sign flips
    const f32x2 ncy = (f32x2){-cy, -cy};
    const f32x2 ncz = (f32x2){-cz, -cz};
    float bv = -1.0f;
    float bx = px[0].x, by = py[0].x, bz = pz[0].x;
    #pragma unroll
    for (int j2 = 0; j2 < 8; ++j2) {
      f32x2 d;
      {
        #pragma clang fp contract(off)
        f32x2 dx = px[j2] + ncx;           // == __fsub_rn(px, cx) per half
        f32x2 dy = py[j2] + ncy;
        f32x2 dz = pz[j2] + ncz;
        d = dx*dx + dy*dy + dz*dz;         // ((x2+y2)+z2), rn, no fma
      }
      float nd0 = fminf(dist[2*j2],   d.x);
      float nd1 = fminf(dist[2*j2+1], d.y);
      dist[2*j2] = nd0; dist[2*j2+1] = nd1;
      if (nd0 > bv) { bv = nd0; bx = px[j2].x; by = py[j2].x; bz = pz[j2].x; }
      if (nd1 > bv) { bv = nd1; bx = px[j2].y; by = py[j2].y; bz = pz[j2].y; }
    }
    float x = bv;
    x = fmax_dpp<0x111,0xF,0xF>(x);   // row_shr:1
    x = fmax_dpp<0x112,0xF,0xF>(x);   // row_shr:2
    x = fmax_dpp<0x114,0xF,0xF>(x);   // row_shr:4
    x = fmax_dpp<0x118,0xF,0xF>(x);   // row_shr:8
    x = fmax_dpp<0x142,0xA,0xF>(x);   // row_bcast:15 -> rows 1,3
    x = fmax_dpp<0x143,0xC,0xF>(x);   // row_bcast:31 -> rows 2,3
    float M = __int_as_float(__builtin_amdgcn_readlane(__float_as_int(x), 63));
    unsigned long long mk = __ballot(bv == M);
    int sl = (int)__builtin_ctzll(mk);
    float wx = __int_as_float(__builtin_amdgcn_readlane(__float_as_int(bx), sl));
    float wy = __int_as_float(__builtin_amdgcn_readlane(__float_as_int(by), sl));
    float wz = __int_as_float(__builtin_amdgcn_readlane(__float_as_int(bz), sl));
    if (lane == 0) pair[i & 1][half][wv4] = make_float4(M, wx, wy, wz);
    __syncthreads();
    const float4* pb = &pair[i & 1][half][0];
    float4 q0 = pb[0], q1 = pb[1], q2 = pb[2], q3 = pb[3];
    float4 best = q0;
    if (q1.x > best.x) best = q1;     // strict > keeps lowest wave (first occ.)
    if (q2.x > best.x) best = q2;
    if (q3.x > best.x) best = q3;
    cx = best.y; cy = best.z; cz = best.w;
  }
}

// ---------------- Ball query: LDS-staged points, 4 queries/block ------------
__global__ __launch_bounds__(256) void k_ballq(const float* __restrict__ xyz,
                                               const float* __restrict__ newxyz,
                                               int* __restrict__ idx) {
  __shared__ float xs[NPTS], ys[NPTS], zs[NPTS];
  const int b  = blockIdx.x >> 8;                 // 256 blocks per batch
  const int s  = (blockIdx.x & 255) * 4 + (threadIdx.x >> 6);
  const int lane = threadIdx.x & 63;
  const float* p = xyz + (size_t)b * 3 * NPTS;
  for (int i = threadIdx.x; i < NPTS; i += 256) {
    xs[i] = p[i];
    ys[i] = p[NPTS + i];
    zs[i] = p[2*NPTS + i];
  }
  __syncthreads();
  const size_t nq = (size_t)(b*NS + s)*3;
  const float nx = newxyz[nq], ny = newxyz[nq+1], nz = newxyz[nq+2];
  const float sn = __fadd_rn(__fadd_rn(__fmul_rn(nx,nx), __fmul_rn(ny,ny)), __fmul_rn(nz,nz));
  const float R2 = (float)(0.2*0.2);
  int* out = idx + (size_t)(b*NS + s) * NK;
  int cnt = 0, first = 0;
  for (int c0 = 0; c0 < NPTS; c0 += 64) {
    int n = c0 + lane;
    float x = xs[n], y = ys[n], z = zs[n];
    float sx = __fadd_rn(__fadd_rn(__fmul_rn(x,x), __fmul_rn(y,y)), __fmul_rn(z,z));
    float dt = __fadd_rn(__fadd_rn(__fmul_rn(nx,x), __fmul_rn(ny,y)), __fmul_rn(nz,z));
    float sqr = __fsub_rn(__fadd_rn(sn, sx), __fmul_rn(2.0f, dt));
    bool inr = (sqr <= R2);
    unsigned long long m = __ballot(inr);
    if (m != 0ull) {
      if (cnt == 0) first = c0 + (int)__builtin_ctzll(m);
      int rank = __popcll(m & ((1ull << lane) - 1ull));
      int pos = cnt + rank;
      if (inr && pos < NK) out[pos] = n;
      cnt += __popcll(m);
      if (cnt >= NK) break;
    }
  }
  int tot = cnt < NK ? cnt : NK;
  if (lane >= tot && lane < NK) out[lane] = first;
}

// ---------------- Moments: S = sum u (6), M = sum u u^T (21) ----------------
// Layer-1 stats are LINEAR in the gathered input u (no relu before BN).
// R13 post-mortem: do NOT fuse finalizes into producers (ticket race +
// cross-XCD visibility). Separate finalize kernels are the proven form.
__global__ __launch_bounds__(256) void k_moments(const float* __restrict__ xyz,
                                                 const float* __restrict__ feat,
                                                 const float* __restrict__ newxyz,
                                                 const int* __restrict__ idx,
                                                 float* __restrict__ accum) {
  const int t = threadIdx.x;
  float S[6] = {0,0,0,0,0,0};
  float Mm[21];
  #pragma unroll
  for (int k = 0; k < 21; ++k) Mm[k] = 0.f;
  for (int it = 0; it < 8; ++it) {
    const int col = blockIdx.x*2048 + it*256 + t;
    const int bs = col >> 5;
    const int b  = bs >> 10;
    const int n  = idx[col];
    const float* xb = xyz  + (size_t)b*3*NPTS;
    const float* fb = feat + (size_t)b*3*NPTS;
    float u[6];
    u[0] = __fsub_rn(xb[n],        newxyz[(size_t)bs*3]);
    u[1] = __fsub_rn(xb[NPTS+n],   newxyz[(size_t)bs*3+1]);
    u[2] = __fsub_rn(xb[2*NPTS+n], newxyz[(size_t)bs*3+2]);
    u[3] = fb[n];
    u[4] = fb[NPTS+n];
    u[5] = fb[2*NPTS+n];
    int k = 0;
    #pragma unroll
    for (int i = 0; i < 6; ++i) {
      S[i] += u[i];
      #pragma unroll
      for (int j = i; j < 6; ++j) { Mm[k] = fmaf(u[i], u[j], Mm[k]); ++k; }
    }
  }
  const int lane = t & 63;
  float* dst = accum + (size_t)(blockIdx.x & (NBUCK-1))*32;   // 27 used of 32
  #pragma unroll
  for (int i = 0; i < 6; ++i) {
    float s = add64_dpp(S[i]);
    if (lane == 63) atomicAdd(&dst[i], s);
  }
  #pragma unroll
  for (int k = 0; k < 21; ++k) {
    float m = add64_dpp(Mm[k]);
    if (lane == 63) atomicAdd(&dst[6+k], m);
  }
}

// ---------------- finalize layer-1 BN from moments (closed form) ------------
__global__ void k_finalize1(const float* __restrict__ accum,
                            const float* __restrict__ w0, const float* __restrict__ b0,
                            const float* __restrict__ g, const float* __restrict__ beta,
                            float* __restrict__ scsh) {
  __shared__ float Sm[27];
  const int t = threadIdx.x;
  if (t < 27) {
    float s = 0.f;
    for (int bkt = 0; bkt < NBUCK; ++bkt) s += accum[(size_t)bkt*32 + t];
    Sm[t] = s;
  }
  __syncthreads();
  if (t < 64) {
    const float* w = w0 + t*6;
    const float b = b0[t];
    float ws = 0.f;
    #pragma unroll
    for (int i = 0; i < 6; ++i) ws = fmaf(w[i], Sm[i], ws);
    float quad = 0.f;
    int k = 6;
    #pragma unroll
    for (int i = 0; i < 6; ++i) {
      #pragma unroll
      for (int j = i; j < 6; ++j) {
        float c = w[i]*w[j];
        if (j > i) c *= 2.f;
        quad = fmaf(c, Sm[k], quad);
        ++k;
      }
    }
    const float n = (float)NT_COLS;
    float mean = (ws + n*b) / n;
    float ex2  = (quad + 2.f*b*ws + n*b*b) / n;
    float var  = ex2 - mean*mean;
    if (var < 0.f) var = 0.f;
    float rs = rsqrtf(var + 1e-5f);
    float sc = g[t] * rs;
    scsh[t]    = sc;
    scsh[64+t] = beta[t] - mean * sc;
  }
}

// ---------------- generic bucket finalize (layers 2/3) ----------------------
__global__ void k_finalize(const float* __restrict__ accum,
                           const float* __restrict__ g, const float* __restrict__ beta,
                           float* __restrict__ scsh, int C) {
  int o = threadIdx.x;
  if (o < C) {
    float s = 0.f, ss = 0.f;
    for (int bkt = 0; bkt < NBUCK; ++bkt) {
      s  += accum[(size_t)bkt*(2*C) + o];
      ss += accum[(size_t)bkt*(2*C) + C + o];
    }
    const float n = (float)NT_COLS;
    float mu  = s / n;
    float var = ss / n - mu*mu;
    if (var < 0.f) var = 0.f;
    float rs = rsqrtf(var + 1e-5f);
    float sc = g[o] * rs;
    scsh[o]   = sc;
    scsh[C+o] = beta[o] - mu * sc;
  }
}

#define XT_STRIDE 72   // bf16 elems; 144 B row -> b128-aligned

// ---------------- Layer 2: recompute-x1 staging + MFMA + fused stats --------
__global__ __launch_bounds__(256) void k_layer2_mfma(
    const float* __restrict__ xyz,
    const float* __restrict__ feat,
    const float* __restrict__ newxyz,
    const int*   __restrict__ idx,
    const float* __restrict__ w0g,   // [64][6]
    const float* __restrict__ b0g,   // [64]
    const float* __restrict__ w1,    // [64][64]
    const float* __restrict__ b1,    // [64]
    const float* __restrict__ scsh,  // sc1[64], sh1[64]
    float*       __restrict__ accum, // [NBUCK][128]
    bf16*        __restrict__ x2) {  // [64][NT_COLS]
  __shared__ short xT[256*XT_STRIDE];
  __shared__ float w0s[64*6];
  __shared__ float b0s[64];
  __shared__ float sc_s[64], sh_s[64], bias_s[64];
  const int t = threadIdx.x;
  const int col0 = blockIdx.x * 256;
  for (int i = t; i < 64*6; i += 256) w0s[i] = w0g[i];
  if (t < 64) {
    b0s[t] = b0g[t];
    sc_s[t] = scsh[t]; sh_s[t] = scsh[64+t];
    bias_s[t] = b1[t];
  }
  __syncthreads();
  {
    const int col = col0 + t;
    const int bs = col >> 5;
    const int b  = bs >> 10;
    const int n  = idx[col];
    const float* xb = xyz  + (size_t)b*3*NPTS;
    const float* fb = feat + (size_t)b*3*NPTS;
    float u[6];
    u[0] = __fsub_rn(xb[n],        newxyz[(size_t)bs*3]);
    u[1] = __fsub_rn(xb[NPTS+n],   newxyz[(size_t)bs*3+1]);
    u[2] = __fsub_rn(xb[2*NPTS+n], newxyz[(size_t)bs*3+2]);
    u[3] = fb[n];
    u[4] = fb[NPTS+n];
    u[5] = fb[2*NPTS+n];
    #pragma unroll
    for (int c0 = 0; c0 < 64; c0 += 8) {
      short8 pk;
      #pragma unroll
      for (int j = 0; j < 8; ++j) {
        const int o = c0 + j;
        float v = b0s[o];
        #pragma unroll
        for (int c = 0; c < 6; ++c) v = fmaf(u[c], w0s[o*6+c], v);
        v = fmaxf(fmaf(v, sc_s[o], sh_s[o]), 0.f);   // BN1 + ReLU
        pk[j] = (short)f2bf_bits(v);
      }
      *((short8*)&xT[t*XT_STRIDE + c0]) = pk;
    }
  }
  __syncthreads();
  const int lane = t & 63, wv = t >> 6;
  const int qd = lane >> 4, ln = lane & 15;
  short8 A[4][2];
  #pragma unroll
  for (int rt = 0; rt < 4; ++rt) {
    #pragma unroll
    for (int kh = 0; kh < 2; ++kh) {
      const float* wp = w1 + (size_t)(rt*16 + ln)*64 + kh*32 + qd*8;
      float4 f0 = *(const float4*)wp;
      float4 f1 = *(const float4*)(wp + 4);
      short8 a;
      a[0]=(short)f2bf_bits(f0.x); a[1]=(short)f2bf_bits(f0.y);
      a[2]=(short)f2bf_bits(f0.z); a[3]=(short)f2bf_bits(f0.w);
      a[4]=(short)f2bf_bits(f1.x); a[5]=(short)f2bf_bits(f1.y);
      a[6]=(short)f2bf_bits(f1.z); a[7]=(short)f2bf_bits(f1.w);
      A[rt][kh] = a;
    }
  }
  floatx4 acc[4][4];
  #pragma unroll
  for (int rt = 0; rt < 4; ++rt)
    #pragma unroll
    for (int ct = 0; ct < 4; ++ct)
      acc[rt][ct] = (floatx4)0.f;
  #pragma unroll
  for (int ct = 0; ct < 4; ++ct) {
    const int coll = wv*64 + ct*16 + ln;
    short8 B0 = *((const short8*)&xT[coll*XT_STRIDE + qd*8]);
    short8 B1 = *((const short8*)&xT[coll*XT_STRIDE + 32 + qd*8]);
    #pragma unroll
    for (int rt = 0; rt < 4; ++rt) {
      acc[rt][ct] = __builtin_amdgcn_mfma_f32_16x16x32_bf16(A[rt][0], B0, acc[rt][ct], 0,0,0);
      acc[rt][ct] = __builtin_amdgcn_mfma_f32_16x16x32_bf16(A[rt][1], B1, acc[rt][ct], 0,0,0);
    }
  }
  float* dst = accum + (size_t)(blockIdx.x & (NBUCK-1))*128;
  #pragma unroll
  for (int rt = 0; rt < 4; ++rt) {
    float s[4]  = {0.f,0.f,0.f,0.f};
    float sq[4] = {0.f,0.f,0.f,0.f};
    #pragma unroll
    for (int ct = 0; ct < 4; ++ct) {
      const int col = col0 + wv*64 + ct*16 + ln;
      #pragma unroll
      for (int r = 0; r < 4; ++r) {
        const int o = rt*16 + qd*4 + r;
        float v = acc[rt][ct][r] + bias_s[o];
        x2[(size_t)o*NT_COLS + col] = __float2bfloat16(v);
        s[r] += v; sq[r] = fmaf(v, v, sq[r]);
      }
    }
    #pragma unroll
    for (int r = 0; r < 4; ++r) {
      float a = add16_dpp(s[r]);
      float q = add16_dpp(sq[r]);
      if (ln == 15) {
        const int o = rt*16 + qd*4 + r;
        atomicAdd(&dst[o], a);
        atomicAdd(&dst[64 + o], q);
      }
    }
  }
}

// ---------------- Layer 3: MFMA + fused stats + fused max-pool --------------
__global__ __launch_bounds__(256) void k_layer3_mfma(
    const bf16*  __restrict__ xin,   // [64][NT_COLS] = x2
    const float* __restrict__ wN,    // [128][64]
    const float* __restrict__ bN,    // [128]
    const float* __restrict__ scsh,  // sc2[64], sh2[64]
    float*       __restrict__ accum, // [NBUCK][256]
    float*       __restrict__ mx) {  // [128][NT_COLS/NK]
  constexpr int CO = 128, RT = CO/16;
  __shared__ short xT[256*XT_STRIDE];
  __shared__ float sc_s[64], sh_s[64], bias_s[CO];
  const int t = threadIdx.x;
  const int col0 = blockIdx.x * 256;
  if (t < 64) { sc_s[t] = scsh[t]; sh_s[t] = scsh[64+t]; }
  if (t < CO) bias_s[t] = bN[t];
  __syncthreads();
  {
    const int col = col0 + t;
    #pragma unroll
    for (int c0 = 0; c0 < 64; c0 += 8) {
      short8 pk;
      #pragma unroll
      for (int j = 0; j < 8; ++j) {
        float v = __bfloat162float(xin[(size_t)(c0+j)*NT_COLS + col]);
        v = fmaxf(fmaf(v, sc_s[c0+j], sh_s[c0+j]), 0.f);
        pk[j] = (short)f2bf_bits(v);
      }
      *((short8*)&xT[t*XT_STRIDE + c0]) = pk;
    }
  }
  __syncthreads();
  const int lane = t & 63, wv = t >> 6;
  const int qd = lane >> 4, ln = lane & 15;
  short8 A[RT][2];
  #pragma unroll
  for (int rt = 0; rt < RT; ++rt) {
    #pragma unroll
    for (int kh = 0; kh < 2; ++kh) {
      const float* wp = wN + (size_t)(rt*16 + ln)*64 + kh*32 + qd*8;
      float4 f0 = *(const float4*)wp;
      float4 f1 = *(const float4*)(wp + 4);
      short8 a;
      a[0]=(short)f2bf_bits(f0.x); a[1]=(short)f2bf_bits(f0.y);
      a[2]=(short)f2bf_bits(f0.z); a[3]=(short)f2bf_bits(f0.w);
      a[4]=(short)f2bf_bits(f1.x); a[5]=(short)f2bf_bits(f1.y);
      a[6]=(short)f2bf_bits(f1.z); a[7]=(short)f2bf_bits(f1.w);
      A[rt][kh] = a;
    }
  }
  floatx4 acc[RT][4];
  #pragma unroll
  for (int rt = 0; rt < RT; ++rt)
    #pragma unroll
    for (int ct = 0; ct < 4; ++ct)
      acc[rt][ct] = (floatx4)0.f;
  #pragma unroll
  for (int ct = 0; ct < 4; ++ct) {
    const int coll = wv*64 + ct*16 + ln;
    short8 B0 = *((const short8*)&xT[coll*XT_STRIDE + qd*8]);
    short8 B1 = *((const short8*)&xT[coll*XT_STRIDE + 32 + qd*8]);
    #pragma unroll
    for (int rt = 0; rt < RT; ++rt) {
      acc[rt][ct] = __builtin_amdgcn_mfma_f32_16x16x32_bf16(A[rt][0], B0, acc[rt][ct], 0,0,0);
      acc[rt][ct] = __builtin_amdgcn_mfma_f32_16x16x32_bf16(A[rt][1], B1, acc[rt][ct], 0,0,0);
    }
  }
  float* dst = accum + (size_t)(blockIdx.x & (NBUCK-1))*(2*CO);
  const int bs0 = (col0 + wv*64) >> 5;     // wave covers bs0, bs0+1
  #pragma unroll
  for (int rt = 0; rt < RT; ++rt) {
    float s[4]  = {0.f,0.f,0.f,0.f};
    float sq[4] = {0.f,0.f,0.f,0.f};
    float mxv[2][4];
    #pragma unroll
    for (int h = 0; h < 2; ++h)
      #pragma unroll
      for (int r = 0; r < 4; ++r) mxv[h][r] = -3.402823466e38f;
    #pragma unroll
    for (int ct = 0; ct < 4; ++ct) {
      #pragma unroll
      for (int r = 0; r < 4; ++r) {
        const int o = rt*16 + qd*4 + r;
        float v = acc[rt][ct][r] + bias_s[o];
        mxv[ct>>1][r] = fmaxf(mxv[ct>>1][r], v);
        s[r] += v; sq[r] = fmaf(v, v, sq[r]);
      }
    }
    #pragma unroll
    for (int h = 0; h < 2; ++h) {
      #pragma unroll
      for (int r = 0; r < 4; ++r) {
        float m = mxv[h][r];
        m = fmax_dpp<0x111,0xF,0xF>(m);
        m = fmax_dpp<0x112,0xF,0xF>(m);
        m = fmax_dpp<0x114,0xF,0xF>(m);
        m = fmax_dpp<0x118,0xF,0xF>(m);
        if (ln == 15) {
          const int o = rt*16 + qd*4 + r;
          mx[(size_t)o*(NT_COLS/NK) + bs0 + h] = m;
        }
      }
    }
    #pragma unroll
    for (int r = 0; r < 4; ++r) {
      float a = add16_dpp(s[r]);
      float q = add16_dpp(sq[r]);
      if (ln == 15) {
        const int o = rt*16 + qd*4 + r;
        atomicAdd(&dst[o], a);
        atomicAdd(&dst[CO + o], q);
      }
    }
  }
}

// ---------------- final BN+ReLU on pooled maxes (fp32 out) ------------------
__global__ __launch_bounds__(256) void k_bnmax(const float* __restrict__ mx,
                                               const float* __restrict__ scsh,
                                               float* __restrict__ out1) {
  const int blk = blockIdx.x;        // 16 b x 128 o
  const int o = blk & 127;
  const int b = blk >> 7;
  const float sc = scsh[o], sh = scsh[128+o];
  const int s = threadIdx.x * 4;
  float4 v = *(const float4*)(mx + (size_t)o*(NT_COLS/NK) + b*NS + s);
  float4 r;
  r.x = fmaxf(fmaf(v.x, sc, sh), 0.f);
  r.y = fmaxf(fmaf(v.y, sc, sh), 0.f);
  r.z = fmaxf(fmaf(v.z, sc, sh), 0.f);
  r.w = fmaxf(fmaf(v.w, sc, sh), 0.f);
  *(float4*)(out1 + (size_t)(b*128 + o)*NS + s) = r;
}

extern "C" void kernel_launch(void* const* d_in, const int* in_sizes, int n_in,
                              void* d_out, int out_size, void* d_ws, size_t ws_size,
                              hipStream_t stream) {
  const float* xyz  = (const float*)d_in[0];
  const float* feat = (const float*)d_in[1];
  const float* w0 = (const float*)d_in[2];
  const float* b0 = (const float*)d_in[3];
  const float* g0 = (const float*)d_in[4];
  const float* bt0= (const float*)d_in[5];
  const float* w1 = (const float*)d_in[6];
  const float* b1 = (const float*)d_in[7];
  const float* g1 = (const float*)d_in[8];
  const float* bt1= (const float*)d_in[9];
  const float* w2 = (const float*)d_in[10];
  const float* b2 = (const float*)d_in[11];
  const float* g2 = (const float*)d_in[12];
  const float* bt2= (const float*)d_in[13];

  float* out0 = (float*)d_out;                     // (B,3,NS) fp32
  float* out1 = out0 + (size_t)NB*3*NS;            // (B,128,NS) fp32

  // Workspace (max offset ~138 MB; ws >= 194 MB proven):
  //   accum@0 (128KB, zeroed by k_fps prologue), scsh@131072,
  //   newxyz@133120, bidx@329728, x2@2426880 (64MB), mx3@136644608 (8MB)
  char* ws = (char*)d_ws;
  float* accum  = (float*)(ws + 0);
  float* acc_l1 = accum;                 // NBUCK x 32 (27 used: S6 + M21)
  float* acc_l2 = accum + 8192;          // NBUCK x 128
  float* acc_l3 = accum + 16384;         // NBUCK x 256
  float* scsh   = (float*)(ws + 131072);
  float* newxyz = (float*)(ws + 133120);
  int*   bidx   = (int*)  (ws + 329728);
  bf16*  x2     = (bf16*) (ws + 2426880);
  float* mx3    = (float*)(ws + 136644608);

  k_fps  <<<NB/4, 1024, 0, stream>>>(xyz, newxyz, out0, accum);
  k_ballq<<<NB*256, 256, 0, stream>>>(xyz, newxyz, bidx);

  k_moments  <<<256, 256, 0, stream>>>(xyz, feat, newxyz, bidx, acc_l1);
  k_finalize1<<<1,    64, 0, stream>>>(acc_l1, w0, b0, g0, bt0, scsh + 0);

  k_layer2_mfma<<<NT_COLS/256, 256, 0, stream>>>(xyz, feat, newxyz, bidx,
                                                 w0, b0, w1, b1, scsh + 0,
                                                 acc_l2, x2);
  k_finalize<<<1, 256, 0, stream>>>(acc_l2, g1, bt1, scsh + 128, 64);

  k_layer3_mfma<<<NT_COLS/256, 256, 0, stream>>>(x2, w2, b2, scsh + 128,
                                                 acc_l3, mx3);
  k_finalize<<<1, 256, 0, stream>>>(acc_l3, g2, bt2, scsh + 256, 128);

  k_bnmax <<<NB*128, 256, 0, stream>>>(mx3, scsh + 256, out1);
}

// Round 4
// 1138.915 us; speedup vs baseline: 1.7945x; 1.7945x over previous
//
#include <hip/hip_runtime.h>
#include <hip/hip_bf16.h>
#include <stdint.h>

#define NB 16
#define NPTS 4096
#define NS 1024
#define NK 32
#define NT_COLS (NB*NS*NK)   // 524288 columns (b*NS+s)*NK + k
#define NBUCK 64             // stat-accumulator buckets

typedef __hip_bfloat16 bf16;
typedef __attribute__((ext_vector_type(8))) short short8;   // 8 bf16 (4 VGPRs)
typedef __attribute__((ext_vector_type(4))) float floatx4;  // MFMA C/D
typedef __attribute__((ext_vector_type(2))) float f32x2;    // pk-fp32 pair

__device__ __forceinline__ unsigned short f2bf_bits(float v) {
  bf16 b = __float2bfloat16(v);
  return *(unsigned short*)&b;
}

// DPP-shifted fmax (verified gfx950 R5/R7/R8). Inactive/OOB src lanes keep old=x.
template<int CTRL, int RM, int BM>
__device__ __forceinline__ float fmax_dpp(float x) {
  int o = __builtin_amdgcn_update_dpp(__float_as_int(x), __float_as_int(x),
                                      CTRL, RM, BM, false);
  return fmaxf(x, __int_as_float(o));
}
// DPP add with zero-fill identity; RM-masked rows add 0 (old=0).
template<int CTRL, int RM>
__device__ __forceinline__ float add_dpp(float x) {
  int o = __builtin_amdgcn_update_dpp(0, __float_as_int(x), CTRL, RM, 0xF, true);
  return __fadd_rn(x, __int_as_float(o));
}
// 16-lane row sum -> lane 15 of each row (mfma C-layout stats).
__device__ __forceinline__ float add16_dpp(float x) {
  x = add_dpp<0x111,0xF>(x); x = add_dpp<0x112,0xF>(x);
  x = add_dpp<0x114,0xF>(x); x = add_dpp<0x118,0xF>(x);
  return x;
}
// full wave64 sum -> lane 63.
__device__ __forceinline__ float add64_dpp(float x) {
  x = add_dpp<0x111,0xF>(x); x = add_dpp<0x112,0xF>(x);
  x = add_dpp<0x114,0xF>(x); x = add_dpp<0x118,0xF>(x);
  x = add_dpp<0x142,0xA>(x);   // row_bcast:15 -> rows 1,3
  x = add_dpp<0x143,0xC>(x);   // row_bcast:31 -> rows 2,3
  return x;
}

// ---------------- FPS: 2 independent R14-batches per block ------------------
// Session ledger:
//  R15 (512thr SAME batch):   552->749  — lockstep waves can't hide chain.
//  R16 (tree argmax+pk):      552->592  — 1 wave/SIMD is latency-bound; the
//                                          argmax chain was already hidden.
//  R17 (4 batches, coords+    552->1777 — interleave WORKS (93% busy on
//       global stores in loop)             active CUs) but per-iter issue
//                                          ballooned: coord-cndmask argmax +
//                                          per-iter global stores whose
//                                          vmcnt(0) drain hit every barrier.
// R18 (this): 2 batches/block, each half runs the R14 code VERBATIM (LDS
// points, INDEX-tracking argmax, LDS sel arrays, zero global stores in the
// loop). Two independent ~740cy-issue chains share each SIMD's ~1300cy
// chain window -> ~750cy effective per batch. LDS 2x61.5KB = 123KB (<160KB
// CU budget, 1 block/CU). Selection per batch is BIT-IDENTICAL to R14.
__global__ __launch_bounds__(512) void k_fps(const float* __restrict__ xyz,
                                             float* __restrict__ newxyz,
                                             float* __restrict__ out0,
                                             float* __restrict__ zero_region) {
  const int t = threadIdx.x;
  {
    float* zp = zero_region + (size_t)blockIdx.x*4096 + t;
    #pragma unroll
    for (int j = 0; j < 8; ++j) zp[j*512] = 0.f;
  }
  const int half = t >> 8;             // 0/1: which batch in this block
  const int tl   = t & 255;            // thread-in-batch (R14's t)
  const int b    = blockIdx.x*2 + half;
  __shared__ float xs[2][NPTS], ys[2][NPTS], zs[2][NPTS];
  __shared__ float selx[2][NS], sely[2][NS], selz[2][NS];
  __shared__ __align__(16) float2 pair[2][2][4];  // [dbuf][half][wave]
  const float* p = xyz + (size_t)b * 3 * NPTS;
  for (int i = tl; i < NPTS; i += 256) {
    xs[half][i] = p[i];
    ys[half][i] = p[NPTS + i];
    zs[half][i] = p[2*NPTS + i];
  }
  __syncthreads();
  f32x2 px[8], py[8], pz[8];
  float dist[16];
  const int p0 = tl * 16;
  #pragma unroll
  for (int j2 = 0; j2 < 8; ++j2) {
    px[j2] = (f32x2){xs[half][p0+2*j2], xs[half][p0+2*j2+1]};
    py[j2] = (f32x2){ys[half][p0+2*j2], ys[half][p0+2*j2+1]};
    pz[j2] = (f32x2){zs[half][p0+2*j2], zs[half][p0+2*j2+1]};
    dist[2*j2] = 1e10f; dist[2*j2+1] = 1e10f;
  }
  const int wv4 = (t >> 6) & 3;        // wave-in-batch 0..3
  int cur = 0;
  for (int i = 0; i < NS; ++i) {
    float cx = xs[half][cur], cy = ys[half][cur], cz = zs[half][cur];
    if (tl == 0) { selx[half][i] = cx; sely[half][i] = cy; selz[half][i] = cz; }
    if (i == NS-1) break;
    const f32x2 ncx = (f32x2){-cx, -cx};   // exact sign flips
    const f32x2 ncy = (f32x2){-cy, -cy};
    const f32x2 ncz = (f32x2){-cz, -cz};
    float bv = -1.0f; int bi = p0;
    #pragma unroll
    for (int j2 = 0; j2 < 8; ++j2) {
      f32x2 d;
      {
        #pragma clang fp contract(off)
        f32x2 dx = px[j2] + ncx;           // == __fsub_rn(px, cx) per half
        f32x2 dy = py[j2] + ncy;
        f32x2 dz = pz[j2] + ncz;
        d = dx*dx + dy*dy + dz*dz;         // ((x2+y2)+z2), rn, no fma
      }
      float nd0 = fminf(dist[2*j2],   d.x);
      float nd1 = fminf(dist[2*j2+1], d.y);
      dist[2*j2] = nd0; dist[2*j2+1] = nd1;
      if (nd0 > bv) { bv = nd0; bi = p0 + 2*j2; }     // strict > => first occ.
      if (nd1 > bv) { bv = nd1; bi = p0 + 2*j2 + 1; }
    }
    float x = bv;
    x = fmax_dpp<0x111,0xF,0xF>(x);   // row_shr:1
    x = fmax_dpp<0x112,0xF,0xF>(x);   // row_shr:2
    x = fmax_dpp<0x114,0xF,0xF>(x);   // row_shr:4
    x = fmax_dpp<0x118,0xF,0xF>(x);   // row_shr:8
    x = fmax_dpp<0x142,0xA,0xF>(x);   // row_bcast:15 -> rows 1,3
    x = fmax_dpp<0x143,0xC,0xF>(x);   // row_bcast:31 -> rows 2,3
    float M = __int_as_float(__builtin_amdgcn_readlane(__float_as_int(x), 63));
    unsigned long long mk = __ballot(bv == M);
    int sl  = (int)__builtin_ctzll(mk);
    int wbi = __builtin_amdgcn_readlane(bi, sl);
    if ((t & 63) == 0) pair[i & 1][half][wv4] = make_float2(M, __int_as_float(wbi));
    __syncthreads();
    const float4* pb = (const float4*)&pair[i & 1][half][0];
    float4 q01 = pb[0], q23 = pb[1];
    float bestv = q01.x; int besti = __float_as_int(q01.y);
    if (q01.z > bestv) { bestv = q01.z; besti = __float_as_int(q01.w); }
    if (q23.x > bestv) { bestv = q23.x; besti = __float_as_int(q23.y); }
    if (q23.z > bestv) { bestv = q23.z; besti = __float_as_int(q23.w); }
    cur = besti;
  }
  __syncthreads();
  for (int i = tl; i < NS; i += 256) {
    float vx = selx[half][i], vy = sely[half][i], vz = selz[half][i];
    size_t q = (size_t)b*3*NS + i;
    out0[q] = vx; out0[q + NS] = vy; out0[q + 2*NS] = vz;   // bit-exact copies
    size_t o = (size_t)(b*NS + i)*3;
    newxyz[o] = vx; newxyz[o+1] = vy; newxyz[o+2] = vz;
  }
}

// ---------------- Ball query: LDS-staged points, 4 queries/block ------------
__global__ __launch_bounds__(256) void k_ballq(const float* __restrict__ xyz,
                                               const float* __restrict__ newxyz,
                                               int* __restrict__ idx) {
  __shared__ float xs[NPTS], ys[NPTS], zs[NPTS];
  const int b  = blockIdx.x >> 8;                 // 256 blocks per batch
  const int s  = (blockIdx.x & 255) * 4 + (threadIdx.x >> 6);
  const int lane = threadIdx.x & 63;
  const float* p = xyz + (size_t)b * 3 * NPTS;
  for (int i = threadIdx.x; i < NPTS; i += 256) {
    xs[i] = p[i];
    ys[i] = p[NPTS + i];
    zs[i] = p[2*NPTS + i];
  }
  __syncthreads();
  const size_t nq = (size_t)(b*NS + s)*3;
  const float nx = newxyz[nq], ny = newxyz[nq+1], nz = newxyz[nq+2];
  const float sn = __fadd_rn(__fadd_rn(__fmul_rn(nx,nx), __fmul_rn(ny,ny)), __fmul_rn(nz,nz));
  const float R2 = (float)(0.2*0.2);
  int* out = idx + (size_t)(b*NS + s) * NK;
  int cnt = 0, first = 0;
  for (int c0 = 0; c0 < NPTS; c0 += 64) {
    int n = c0 + lane;
    float x = xs[n], y = ys[n], z = zs[n];
    float sx = __fadd_rn(__fadd_rn(__fmul_rn(x,x), __fmul_rn(y,y)), __fmul_rn(z,z));
    float dt = __fadd_rn(__fadd_rn(__fmul_rn(nx,x), __fmul_rn(ny,y)), __fmul_rn(nz,z));
    float sqr = __fsub_rn(__fadd_rn(sn, sx), __fmul_rn(2.0f, dt));
    bool inr = (sqr <= R2);
    unsigned long long m = __ballot(inr);
    if (m != 0ull) {
      if (cnt == 0) first = c0 + (int)__builtin_ctzll(m);
      int rank = __popcll(m & ((1ull << lane) - 1ull));
      int pos = cnt + rank;
      if (inr && pos < NK) out[pos] = n;
      cnt += __popcll(m);
      if (cnt >= NK) break;
    }
  }
  int tot = cnt < NK ? cnt : NK;
  if (lane >= tot && lane < NK) out[lane] = first;
}

// ---------------- Moments: S = sum u (6), M = sum u u^T (21) ----------------
// Layer-1 stats are LINEAR in the gathered input u (no relu before BN).
// R13 post-mortem: do NOT fuse finalizes into producers (ticket race +
// cross-XCD visibility). Separate finalize kernels are the proven form.
__global__ __launch_bounds__(256) void k_moments(const float* __restrict__ xyz,
                                                 const float* __restrict__ feat,
                                                 const float* __restrict__ newxyz,
                                                 const int* __restrict__ idx,
                                                 float* __restrict__ accum) {
  const int t = threadIdx.x;
  float S[6] = {0,0,0,0,0,0};
  float Mm[21];
  #pragma unroll
  for (int k = 0; k < 21; ++k) Mm[k] = 0.f;
  for (int it = 0; it < 8; ++it) {
    const int col = blockIdx.x*2048 + it*256 + t;
    const int bs = col >> 5;
    const int b  = bs >> 10;
    const int n  = idx[col];
    const float* xb = xyz  + (size_t)b*3*NPTS;
    const float* fb = feat + (size_t)b*3*NPTS;
    float u[6];
    u[0] = __fsub_rn(xb[n],        newxyz[(size_t)bs*3]);
    u[1] = __fsub_rn(xb[NPTS+n],   newxyz[(size_t)bs*3+1]);
    u[2] = __fsub_rn(xb[2*NPTS+n], newxyz[(size_t)bs*3+2]);
    u[3] = fb[n];
    u[4] = fb[NPTS+n];
    u[5] = fb[2*NPTS+n];
    int k = 0;
    #pragma unroll
    for (int i = 0; i < 6; ++i) {
      S[i] += u[i];
      #pragma unroll
      for (int j = i; j < 6; ++j) { Mm[k] = fmaf(u[i], u[j], Mm[k]); ++k; }
    }
  }
  const int lane = t & 63;
  float* dst = accum + (size_t)(blockIdx.x & (NBUCK-1))*32;   // 27 used of 32
  #pragma unroll
  for (int i = 0; i < 6; ++i) {
    float s = add64_dpp(S[i]);
    if (lane == 63) atomicAdd(&dst[i], s);
  }
  #pragma unroll
  for (int k = 0; k < 21; ++k) {
    float m = add64_dpp(Mm[k]);
    if (lane == 63) atomicAdd(&dst[6+k], m);
  }
}

// ---------------- finalize layer-1 BN from moments (closed form) ------------
__global__ void k_finalize1(const float* __restrict__ accum,
                            const float* __restrict__ w0, const float* __restrict__ b0,
                            const float* __restrict__ g, const float* __restrict__ beta,
                            float* __restrict__ scsh) {
  __shared__ float Sm[27];
  const int t = threadIdx.x;
  if (t < 27) {
    float s = 0.f;
    for (int bkt = 0; bkt < NBUCK; ++bkt) s += accum[(size_t)bkt*32 + t];
    Sm[t] = s;
  }
  __syncthreads();
  if (t < 64) {
    const float* w = w0 + t*6;
    const float b = b0[t];
    float ws = 0.f;
    #pragma unroll
    for (int i = 0; i < 6; ++i) ws = fmaf(w[i], Sm[i], ws);
    float quad = 0.f;
    int k = 6;
    #pragma unroll
    for (int i = 0; i < 6; ++i) {
      #pragma unroll
      for (int j = i; j < 6; ++j) {
        float c = w[i]*w[j];
        if (j > i) c *= 2.f;
        quad = fmaf(c, Sm[k], quad);
        ++k;
      }
    }
    const float n = (float)NT_COLS;
    float mean = (ws + n*b) / n;
    float ex2  = (quad + 2.f*b*ws + n*b*b) / n;
    float var  = ex2 - mean*mean;
    if (var < 0.f) var = 0.f;
    float rs = rsqrtf(var + 1e-5f);
    float sc = g[t] * rs;
    scsh[t]    = sc;
    scsh[64+t] = beta[t] - mean * sc;
  }
}

// ---------------- generic bucket finalize (layers 2/3) ----------------------
__global__ void k_finalize(const float* __restrict__ accum,
                           const float* __restrict__ g, const float* __restrict__ beta,
                           float* __restrict__ scsh, int C) {
  int o = threadIdx.x;
  if (o < C) {
    float s = 0.f, ss = 0.f;
    for (int bkt = 0; bkt < NBUCK; ++bkt) {
      s  += accum[(size_t)bkt*(2*C) + o];
      ss += accum[(size_t)bkt*(2*C) + C + o];
    }
    const float n = (float)NT_COLS;
    float mu  = s / n;
    float var = ss / n - mu*mu;
    if (var < 0.f) var = 0.f;
    float rs = rsqrtf(var + 1e-5f);
    float sc = g[o] * rs;
    scsh[o]   = sc;
    scsh[C+o] = beta[o] - mu * sc;
  }
}

#define XT_STRIDE 72   // bf16 elems; 144 B row -> b128-aligned

// ---------------- Layer 2: recompute-x1 staging + MFMA + fused stats --------
__global__ __launch_bounds__(256) void k_layer2_mfma(
    const float* __restrict__ xyz,
    const float* __restrict__ feat,
    const float* __restrict__ newxyz,
    const int*   __restrict__ idx,
    const float* __restrict__ w0g,   // [64][6]
    const float* __restrict__ b0g,   // [64]
    const float* __restrict__ w1,    // [64][64]
    const float* __restrict__ b1,    // [64]
    const float* __restrict__ scsh,  // sc1[64], sh1[64]
    float*       __restrict__ accum, // [NBUCK][128]
    bf16*        __restrict__ x2) {  // [64][NT_COLS]
  __shared__ short xT[256*XT_STRIDE];
  __shared__ float w0s[64*6];
  __shared__ float b0s[64];
  __shared__ float sc_s[64], sh_s[64], bias_s[64];
  const int t = threadIdx.x;
  const int col0 = blockIdx.x * 256;
  for (int i = t; i < 64*6; i += 256) w0s[i] = w0g[i];
  if (t < 64) {
    b0s[t] = b0g[t];
    sc_s[t] = scsh[t]; sh_s[t] = scsh[64+t];
    bias_s[t] = b1[t];
  }
  __syncthreads();
  {
    const int col = col0 + t;
    const int bs = col >> 5;
    const int b  = bs >> 10;
    const int n  = idx[col];
    const float* xb = xyz  + (size_t)b*3*NPTS;
    const float* fb = feat + (size_t)b*3*NPTS;
    float u[6];
    u[0] = __fsub_rn(xb[n],        newxyz[(size_t)bs*3]);
    u[1] = __fsub_rn(xb[NPTS+n],   newxyz[(size_t)bs*3+1]);
    u[2] = __fsub_rn(xb[2*NPTS+n], newxyz[(size_t)bs*3+2]);
    u[3] = fb[n];
    u[4] = fb[NPTS+n];
    u[5] = fb[2*NPTS+n];
    #pragma unroll
    for (int c0 = 0; c0 < 64; c0 += 8) {
      short8 pk;
      #pragma unroll
      for (int j = 0; j < 8; ++j) {
        const int o = c0 + j;
        float v = b0s[o];
        #pragma unroll
        for (int c = 0; c < 6; ++c) v = fmaf(u[c], w0s[o*6+c], v);
        v = fmaxf(fmaf(v, sc_s[o], sh_s[o]), 0.f);   // BN1 + ReLU
        pk[j] = (short)f2bf_bits(v);
      }
      *((short8*)&xT[t*XT_STRIDE + c0]) = pk;
    }
  }
  __syncthreads();
  const int lane = t & 63, wv = t >> 6;
  const int qd = lane >> 4, ln = lane & 15;
  short8 A[4][2];
  #pragma unroll
  for (int rt = 0; rt < 4; ++rt) {
    #pragma unroll
    for (int kh = 0; kh < 2; ++kh) {
      const float* wp = w1 + (size_t)(rt*16 + ln)*64 + kh*32 + qd*8;
      float4 f0 = *(const float4*)wp;
      float4 f1 = *(const float4*)(wp + 4);
      short8 a;
      a[0]=(short)f2bf_bits(f0.x); a[1]=(short)f2bf_bits(f0.y);
      a[2]=(short)f2bf_bits(f0.z); a[3]=(short)f2bf_bits(f0.w);
      a[4]=(short)f2bf_bits(f1.x); a[5]=(short)f2bf_bits(f1.y);
      a[6]=(short)f2bf_bits(f1.z); a[7]=(short)f2bf_bits(f1.w);
      A[rt][kh] = a;
    }
  }
  floatx4 acc[4][4];
  #pragma unroll
  for (int rt = 0; rt < 4; ++rt)
    #pragma unroll
    for (int ct = 0; ct < 4; ++ct)
      acc[rt][ct] = (floatx4)0.f;
  #pragma unroll
  for (int ct = 0; ct < 4; ++ct) {
    const int coll = wv*64 + ct*16 + ln;
    short8 B0 = *((const short8*)&xT[coll*XT_STRIDE + qd*8]);
    short8 B1 = *((const short8*)&xT[coll*XT_STRIDE + 32 + qd*8]);
    #pragma unroll
    for (int rt = 0; rt < 4; ++rt) {
      acc[rt][ct] = __builtin_amdgcn_mfma_f32_16x16x32_bf16(A[rt][0], B0, acc[rt][ct], 0,0,0);
      acc[rt][ct] = __builtin_amdgcn_mfma_f32_16x16x32_bf16(A[rt][1], B1, acc[rt][ct], 0,0,0);
    }
  }
  float* dst = accum + (size_t)(blockIdx.x & (NBUCK-1))*128;
  #pragma unroll
  for (int rt = 0; rt < 4; ++rt) {
    float s[4]  = {0.f,0.f,0.f,0.f};
    float sq[4] = {0.f,0.f,0.f,0.f};
    #pragma unroll
    for (int ct = 0; ct < 4; ++ct) {
      const int col = col0 + wv*64 + ct*16 + ln;
      #pragma unroll
      for (int r = 0; r < 4; ++r) {
        const int o = rt*16 + qd*4 + r;
        float v = acc[rt][ct][r] + bias_s[o];
        x2[(size_t)o*NT_COLS + col] = __float2bfloat16(v);
        s[r] += v; sq[r] = fmaf(v, v, sq[r]);
      }
    }
    #pragma unroll
    for (int r = 0; r < 4; ++r) {
      float a = add16_dpp(s[r]);
      float q = add16_dpp(sq[r]);
      if (ln == 15) {
        const int o = rt*16 + qd*4 + r;
        atomicAdd(&dst[o], a);
        atomicAdd(&dst[64 + o], q);
      }
    }
  }
}

// ---------------- Layer 3: MFMA + fused stats + fused max-pool --------------
__global__ __launch_bounds__(256) void k_layer3_mfma(
    const bf16*  __restrict__ xin,   // [64][NT_COLS] = x2
    const float* __restrict__ wN,    // [128][64]
    const float* __restrict__ bN,    // [128]
    const float* __restrict__ scsh,  // sc2[64], sh2[64]
    float*       __restrict__ accum, // [NBUCK][256]
    float*       __restrict__ mx) {  // [128][NT_COLS/NK]
  constexpr int CO = 128, RT = CO/16;
  __shared__ short xT[256*XT_STRIDE];
  __shared__ float sc_s[64], sh_s[64], bias_s[CO];
  const int t = threadIdx.x;
  const int col0 = blockIdx.x * 256;
  if (t < 64) { sc_s[t] = scsh[t]; sh_s[t] = scsh[64+t]; }
  if (t < CO) bias_s[t] = bN[t];
  __syncthreads();
  {
    const int col = col0 + t;
    #pragma unroll
    for (int c0 = 0; c0 < 64; c0 += 8) {
      short8 pk;
      #pragma unroll
      for (int j = 0; j < 8; ++j) {
        float v = __bfloat162float(xin[(size_t)(c0+j)*NT_COLS + col]);
        v = fmaxf(fmaf(v, sc_s[c0+j], sh_s[c0+j]), 0.f);
        pk[j] = (short)f2bf_bits(v);
      }
      *((short8*)&xT[t*XT_STRIDE + c0]) = pk;
    }
  }
  __syncthreads();
  const int lane = t & 63, wv = t >> 6;
  const int qd = lane >> 4, ln = lane & 15;
  short8 A[RT][2];
  #pragma unroll
  for (int rt = 0; rt < RT; ++rt) {
    #pragma unroll
    for (int kh = 0; kh < 2; ++kh) {
      const float* wp = wN + (size_t)(rt*16 + ln)*64 + kh*32 + qd*8;
      float4 f0 = *(const float4*)wp;
      float4 f1 = *(const float4*)(wp + 4);
      short8 a;
      a[0]=(short)f2bf_bits(f0.x); a[1]=(short)f2bf_bits(f0.y);
      a[2]=(short)f2bf_bits(f0.z); a[3]=(short)f2bf_bits(f0.w);
      a[4]=(short)f2bf_bits(f1.x); a[5]=(short)f2bf_bits(f1.y);
      a[6]=(short)f2bf_bits(f1.z); a[7]=(short)f2bf_bits(f1.w);
      A[rt][kh] = a;
    }
  }
  floatx4 acc[RT][4];
  #pragma unroll
  for (int rt = 0; rt < RT; ++rt)
    #pragma unroll
    for (int ct = 0; ct < 4; ++ct)
      acc[rt][ct] = (floatx4)0.f;
  #pragma unroll
  for (int ct = 0; ct < 4; ++ct) {
    const int coll = wv*64 + ct*16 + ln;
    short8 B0 = *((const short8*)&xT[coll*XT_STRIDE + qd*8]);
    short8 B1 = *((const short8*)&xT[coll*XT_STRIDE + 32 + qd*8]);
    #pragma unroll
    for (int rt = 0; rt < RT; ++rt) {
      acc[rt][ct] = __builtin_amdgcn_mfma_f32_16x16x32_bf16(A[rt][0], B0, acc[rt][ct], 0,0,0);
      acc[rt][ct] = __builtin_amdgcn_mfma_f32_16x16x32_bf16(A[rt][1], B1, acc[rt][ct], 0,0,0);
    }
  }
  float* dst = accum + (size_t)(blockIdx.x & (NBUCK-1))*(2*CO);
  const int bs0 = (col0 + wv*64) >> 5;     // wave covers bs0, bs0+1
  #pragma unroll
  for (int rt = 0; rt < RT; ++rt) {
    float s[4]  = {0.f,0.f,0.f,0.f};
    float sq[4] = {0.f,0.f,0.f,0.f};
    float mxv[2][4];
    #pragma unroll
    for (int h = 0; h < 2; ++h)
      #pragma unroll
      for (int r = 0; r < 4; ++r) mxv[h][r] = -3.402823466e38f;
    #pragma unroll
    for (int ct = 0; ct < 4; ++ct) {
      #pragma unroll
      for (int r = 0; r < 4; ++r) {
        const int o = rt*16 + qd*4 + r;
        float v = acc[rt][ct][r] + bias_s[o];
        mxv[ct>>1][r] = fmaxf(mxv[ct>>1][r], v);
        s[r] += v; sq[r] = fmaf(v, v, sq[r]);
      }
    }
    #pragma unroll
    for (int h = 0; h < 2; ++h) {
      #pragma unroll
      for (int r = 0; r < 4; ++r) {
        float m = mxv[h][r];
        m = fmax_dpp<0x111,0xF,0xF>(m);
        m = fmax_dpp<0x112,0xF,0xF>(m);
        m = fmax_dpp<0x114,0xF,0xF>(m);
        m = fmax_dpp<0x118,0xF,0xF>(m);
        if (ln == 15) {
          const int o = rt*16 + qd*4 + r;
          mx[(size_t)o*(NT_COLS/NK) + bs0 + h] = m;
        }
      }
    }
    #pragma unroll
    for (int r = 0; r < 4; ++r) {
      float a = add16_dpp(s[r]);
      float q = add16_dpp(sq[r]);
      if (ln == 15) {
        const int o = rt*16 + qd*4 + r;
        atomicAdd(&dst[o], a);
        atomicAdd(&dst[CO + o], q);
      }
    }
  }
}

// ---------------- final BN+ReLU on pooled maxes (fp32 out) ------------------
__global__ __launch_bounds__(256) void k_bnmax(const float* __restrict__ mx,
                                               const float* __restrict__ scsh,
                                               float* __restrict__ out1) {
  const int blk = blockIdx.x;        // 16 b x 128 o
  const int o = blk & 127;
  const int b = blk >> 7;
  const float sc = scsh[o], sh = scsh[128+o];
  const int s = threadIdx.x * 4;
  float4 v = *(const float4*)(mx + (size_t)o*(NT_COLS/NK) + b*NS + s);
  float4 r;
  r.x = fmaxf(fmaf(v.x, sc, sh), 0.f);
  r.y = fmaxf(fmaf(v.y, sc, sh), 0.f);
  r.z = fmaxf(fmaf(v.z, sc, sh), 0.f);
  r.w = fmaxf(fmaf(v.w, sc, sh), 0.f);
  *(float4*)(out1 + (size_t)(b*128 + o)*NS + s) = r;
}

extern "C" void kernel_launch(void* const* d_in, const int* in_sizes, int n_in,
                              void* d_out, int out_size, void* d_ws, size_t ws_size,
                              hipStream_t stream) {
  const float* xyz  = (const float*)d_in[0];
  const float* feat = (const float*)d_in[1];
  const float* w0 = (const float*)d_in[2];
  const float* b0 = (const float*)d_in[3];
  const float* g0 = (const float*)d_in[4];
  const float* bt0= (const float*)d_in[5];
  const float* w1 = (const float*)d_in[6];
  const float* b1 = (const float*)d_in[7];
  const float* g1 = (const float*)d_in[8];
  const float* bt1= (const float*)d_in[9];
  const float* w2 = (const float*)d_in[10];
  const float* b2 = (const float*)d_in[11];
  const float* g2 = (const float*)d_in[12];
  const float* bt2= (const float*)d_in[13];

  float* out0 = (float*)d_out;                     // (B,3,NS) fp32
  float* out1 = out0 + (size_t)NB*3*NS;            // (B,128,NS) fp32

  // Workspace (max offset ~138 MB; ws >= 194 MB proven):
  //   accum@0 (128KB, zeroed by k_fps prologue), scsh@131072,
  //   newxyz@133120, bidx@329728, x2@2426880 (64MB), mx3@136644608 (8MB)
  char* ws = (char*)d_ws;
  float* accum  = (float*)(ws + 0);
  float* acc_l1 = accum;                 // NBUCK x 32 (27 used: S6 + M21)
  float* acc_l2 = accum + 8192;          // NBUCK x 128
  float* acc_l3 = accum + 16384;         // NBUCK x 256
  float* scsh   = (float*)(ws + 131072);
  float* newxyz = (float*)(ws + 133120);
  int*   bidx   = (int*)  (ws + 329728);
  bf16*  x2     = (bf16*) (ws + 2426880);
  float* mx3    = (float*)(ws + 136644608);

  k_fps  <<<NB/2, 512, 0, stream>>>(xyz, newxyz, out0, accum);
  k_ballq<<<NB*256, 256, 0, stream>>>(xyz, newxyz, bidx);

  k_moments  <<<256, 256, 0, stream>>>(xyz, feat, newxyz, bidx, acc_l1);
  k_finalize1<<<1,    64, 0, stream>>>(acc_l1, w0, b0, g0, bt0, scsh + 0);

  k_layer2_mfma<<<NT_COLS/256, 256, 0, stream>>>(xyz, feat, newxyz, bidx,
                                                 w0, b0, w1, b1, scsh + 0,
                                                 acc_l2, x2);
  k_finalize<<<1, 256, 0, stream>>>(acc_l2, g1, bt1, scsh + 128, 64);

  k_layer3_mfma<<<NT_COLS/256, 256, 0, stream>>>(x2, w2, b2, scsh + 128,
                                                 acc_l3, mx3);
  k_finalize<<<1, 256, 0, stream>>>(acc_l3, g2, bt2, scsh + 256, 128);

  k_bnmax <<<NB*128, 256, 0, stream>>>(mx3, scsh + 256, out1);
}

// Round 5
// 803.909 us; speedup vs baseline: 2.5423x; 1.4167x over previous
//
#include <hip/hip_runtime.h>
#include <hip/hip_bf16.h>
#include <stdint.h>

#define NB 16
#define NPTS 4096
#define NS 1024
#define NK 32
#define NT_COLS (NB*NS*NK)   // 524288 columns (b*NS+s)*NK + k
#define NBUCK 64             // stat-accumulator buckets

typedef __hip_bfloat16 bf16;
typedef __attribute__((ext_vector_type(8))) short short8;   // 8 bf16 (4 VGPRs)
typedef __attribute__((ext_vector_type(4))) float floatx4;  // MFMA C/D
typedef __attribute__((ext_vector_type(2))) float f32x2;    // pk-fp32 pair

__device__ __forceinline__ unsigned short f2bf_bits(float v) {
  bf16 b = __float2bfloat16(v);
  return *(unsigned short*)&b;
}

// DPP-shifted fmax (verified gfx950 R5/R7/R8). Inactive/OOB src lanes keep old=x.
template<int CTRL, int RM, int BM>
__device__ __forceinline__ float fmax_dpp(float x) {
  int o = __builtin_amdgcn_update_dpp(__float_as_int(x), __float_as_int(x),
                                      CTRL, RM, BM, false);
  return fmaxf(x, __int_as_float(o));
}
// DPP add with zero-fill identity; RM-masked rows add 0 (old=0).
template<int CTRL, int RM>
__device__ __forceinline__ float add_dpp(float x) {
  int o = __builtin_amdgcn_update_dpp(0, __float_as_int(x), CTRL, RM, 0xF, true);
  return __fadd_rn(x, __int_as_float(o));
}
// 16-lane row sum -> lane 15 of each row (mfma C-layout stats).
__device__ __forceinline__ float add16_dpp(float x) {
  x = add_dpp<0x111,0xF>(x); x = add_dpp<0x112,0xF>(x);
  x = add_dpp<0x114,0xF>(x); x = add_dpp<0x118,0xF>(x);
  return x;
}
// full wave64 sum -> lane 63.
__device__ __forceinline__ float add64_dpp(float x) {
  x = add_dpp<0x111,0xF>(x); x = add_dpp<0x112,0xF>(x);
  x = add_dpp<0x114,0xF>(x); x = add_dpp<0x118,0xF>(x);
  x = add_dpp<0x142,0xA>(x);   // row_bcast:15 -> rows 1,3
  x = add_dpp<0x143,0xC>(x);   // row_bcast:31 -> rows 2,3
  return x;
}

// ---------------- FPS: R14 structure + defer-index argmax (chain cut) -------
// Session ledger (k_fps):
//  R14/R0 base:             552us  — 1296cy/iter = ~740 issue + ~550 serial
//                                     (post-barrier exchange/broadcast chain)
//  R15 512thr same batch:   749us  — lockstep waves can't hide chain stalls
//  R16 tree argmax (pv/pi): 592us  — per-node index selects kept chain serial
//  R17 4 batches+coords:   1777us  — issue ballooned (coord cndmask + stores)
//  R18 2 batches/block:     873us  — stall constant 553cy; packing only adds
//                                     issue. WALL time = one batch's chain.
// Conclusion: only lever is shortening the per-iteration critical path.
// R19 (this): defer-index argmax. Dist loop updates dist[] ONLY (no index
// tracking -> removes the 16-deep cmp/sel serial chain ~128cy). Lane max via
// balanced fmaxf triples (-> v_max3_f32, 8 ops depth 3). Index recovered
// AFTER bv via 16-wide equality mask + ctz — independent of the 6-level DPP
// + readlane + ballot chain, so it hides under it. Tie semantics identical:
// smallest j with dist[j]==bv == ascending strict-> first occurrence; wave
// (ctz ballot) and cross-wave (ascending strict >) selection unchanged.
__global__ __launch_bounds__(256) void k_fps(const float* __restrict__ xyz,
                                             float* __restrict__ newxyz,
                                             float* __restrict__ out0,
                                             float* __restrict__ zero_region) {
  const int b = blockIdx.x;
  const int t = threadIdx.x;
  {
    float* zp = zero_region + (size_t)b*2048 + t;
    #pragma unroll
    for (int j = 0; j < 8; ++j) zp[j*256] = 0.f;
  }
  __shared__ float xs[NPTS], ys[NPTS], zs[NPTS];
  __shared__ float selx[NS], sely[NS], selz[NS];
  __shared__ float2 pair[2][4];   // double-buffered (value, idx-bits) per wave
  const float* p = xyz + (size_t)b * 3 * NPTS;
  for (int i = t; i < NPTS; i += 256) {
    xs[i] = p[i];
    ys[i] = p[NPTS + i];
    zs[i] = p[2*NPTS + i];
  }
  __syncthreads();
  f32x2 px[8], py[8], pz[8];
  float dist[16];
  const int p0 = t * 16;
  #pragma unroll
  for (int j2 = 0; j2 < 8; ++j2) {
    px[j2] = (f32x2){xs[p0+2*j2], xs[p0+2*j2+1]};
    py[j2] = (f32x2){ys[p0+2*j2], ys[p0+2*j2+1]};
    pz[j2] = (f32x2){zs[p0+2*j2], zs[p0+2*j2+1]};
    dist[2*j2] = 1e10f; dist[2*j2+1] = 1e10f;
  }
  const int lane = t & 63, wv = t >> 6;
  int cur = 0;
  for (int i = 0; i < NS; ++i) {
    float cx = xs[cur], cy = ys[cur], cz = zs[cur];
    if (t == 0) { selx[i] = cx; sely[i] = cy; selz[i] = cz; }
    if (i == NS-1) break;
    const f32x2 ncx = (f32x2){-cx, -cx};   // exact sign flips
    const f32x2 ncy = (f32x2){-cy, -cy};
    const f32x2 ncz = (f32x2){-cz, -cz};
    // dist update only — no index tracking in the hot loop
    #pragma unroll
    for (int j2 = 0; j2 < 8; ++j2) {
      f32x2 d;
      {
        #pragma clang fp contract(off)
        f32x2 dx = px[j2] + ncx;           // == __fsub_rn(px, cx) per half
        f32x2 dy = py[j2] + ncy;
        f32x2 dz = pz[j2] + ncz;
        d = dx*dx + dy*dy + dz*dz;         // ((x2+y2)+z2), rn, no fma
      }
      dist[2*j2]   = fminf(dist[2*j2],   d.x);
      dist[2*j2+1] = fminf(dist[2*j2+1], d.y);
    }
    // lane max: balanced fmaxf triples -> v_max3_f32, 8 ops, depth 3
    float a0 = fmaxf(fmaxf(dist[0],  dist[1]),  dist[2]);
    float a1 = fmaxf(fmaxf(dist[3],  dist[4]),  dist[5]);
    float a2 = fmaxf(fmaxf(dist[6],  dist[7]),  dist[8]);
    float a3 = fmaxf(fmaxf(dist[9],  dist[10]), dist[11]);
    float a4 = fmaxf(fmaxf(dist[12], dist[13]), dist[14]);
    float b0 = fmaxf(fmaxf(a0, a1), a2);
    float b1 = fmaxf(fmaxf(a3, a4), dist[15]);
    float bv = fmaxf(b0, b1);
    // wave max via DPP chain (serial ~130cy) ...
    float x = bv;
    x = fmax_dpp<0x111,0xF,0xF>(x);   // row_shr:1
    x = fmax_dpp<0x112,0xF,0xF>(x);   // row_shr:2
    x = fmax_dpp<0x114,0xF,0xF>(x);   // row_shr:4
    x = fmax_dpp<0x118,0xF,0xF>(x);   // row_shr:8
    x = fmax_dpp<0x142,0xA,0xF>(x);   // row_bcast:15 -> rows 1,3
    x = fmax_dpp<0x143,0xC,0xF>(x);   // row_bcast:31 -> rows 2,3
    // ... while the index recovery (independent of DPP chain) hides under it:
    unsigned msk = 0u;
    #pragma unroll
    for (int j = 0; j < 16; ++j)
      msk |= (dist[j] == bv) ? (1u << j) : 0u;
    int bi = p0 + (int)__builtin_ctz(msk);   // smallest j == first occurrence
    float M = __int_as_float(__builtin_amdgcn_readlane(__float_as_int(x), 63));
    unsigned long long mk = __ballot(bv == M);
    int sl  = (int)__builtin_ctzll(mk);
    int wbi = __builtin_amdgcn_readlane(bi, sl);
    if ((t & 63) == 0) pair[i & 1][wv] = make_float2(M, __int_as_float(wbi));
    __syncthreads();
    const float4* pb = (const float4*)&pair[i & 1][0];
    float4 q01 = pb[0], q23 = pb[1];
    float bestv = q01.x; int besti = __float_as_int(q01.y);
    if (q01.z > bestv) { bestv = q01.z; besti = __float_as_int(q01.w); }
    if (q23.x > bestv) { bestv = q23.x; besti = __float_as_int(q23.y); }
    if (q23.z > bestv) { bestv = q23.z; besti = __float_as_int(q23.w); }
    cur = besti;
  }
  __syncthreads();
  for (int i = t; i < NS; i += 256) {
    float vx = selx[i], vy = sely[i], vz = selz[i];
    size_t q = (size_t)b*3*NS + i;
    out0[q] = vx; out0[q + NS] = vy; out0[q + 2*NS] = vz;   // bit-exact copies
    size_t o = (size_t)(b*NS + i)*3;
    newxyz[o] = vx; newxyz[o+1] = vy; newxyz[o+2] = vz;
  }
}

// ---------------- Ball query: LDS-staged points, 4 queries/block ------------
__global__ __launch_bounds__(256) void k_ballq(const float* __restrict__ xyz,
                                               const float* __restrict__ newxyz,
                                               int* __restrict__ idx) {
  __shared__ float xs[NPTS], ys[NPTS], zs[NPTS];
  const int b  = blockIdx.x >> 8;                 // 256 blocks per batch
  const int s  = (blockIdx.x & 255) * 4 + (threadIdx.x >> 6);
  const int lane = threadIdx.x & 63;
  const float* p = xyz + (size_t)b * 3 * NPTS;
  for (int i = threadIdx.x; i < NPTS; i += 256) {
    xs[i] = p[i];
    ys[i] = p[NPTS + i];
    zs[i] = p[2*NPTS + i];
  }
  __syncthreads();
  const size_t nq = (size_t)(b*NS + s)*3;
  const float nx = newxyz[nq], ny = newxyz[nq+1], nz = newxyz[nq+2];
  const float sn = __fadd_rn(__fadd_rn(__fmul_rn(nx,nx), __fmul_rn(ny,ny)), __fmul_rn(nz,nz));
  const float R2 = (float)(0.2*0.2);
  int* out = idx + (size_t)(b*NS + s) * NK;
  int cnt = 0, first = 0;
  for (int c0 = 0; c0 < NPTS; c0 += 64) {
    int n = c0 + lane;
    float x = xs[n], y = ys[n], z = zs[n];
    float sx = __fadd_rn(__fadd_rn(__fmul_rn(x,x), __fmul_rn(y,y)), __fmul_rn(z,z));
    float dt = __fadd_rn(__fadd_rn(__fmul_rn(nx,x), __fmul_rn(ny,y)), __fmul_rn(nz,z));
    float sqr = __fsub_rn(__fadd_rn(sn, sx), __fmul_rn(2.0f, dt));
    bool inr = (sqr <= R2);
    unsigned long long m = __ballot(inr);
    if (m != 0ull) {
      if (cnt == 0) first = c0 + (int)__builtin_ctzll(m);
      int rank = __popcll(m & ((1ull << lane) - 1ull));
      int pos = cnt + rank;
      if (inr && pos < NK) out[pos] = n;
      cnt += __popcll(m);
      if (cnt >= NK) break;
    }
  }
  int tot = cnt < NK ? cnt : NK;
  if (lane >= tot && lane < NK) out[lane] = first;
}

// ---------------- Moments: S = sum u (6), M = sum u u^T (21) ----------------
// Layer-1 stats are LINEAR in the gathered input u (no relu before BN).
// R13 post-mortem: do NOT fuse finalizes into producers (ticket race +
// cross-XCD visibility). Separate finalize kernels are the proven form.
__global__ __launch_bounds__(256) void k_moments(const float* __restrict__ xyz,
                                                 const float* __restrict__ feat,
                                                 const float* __restrict__ newxyz,
                                                 const int* __restrict__ idx,
                                                 float* __restrict__ accum) {
  const int t = threadIdx.x;
  float S[6] = {0,0,0,0,0,0};
  float Mm[21];
  #pragma unroll
  for (int k = 0; k < 21; ++k) Mm[k] = 0.f;
  for (int it = 0; it < 8; ++it) {
    const int col = blockIdx.x*2048 + it*256 + t;
    const int bs = col >> 5;
    const int b  = bs >> 10;
    const int n  = idx[col];
    const float* xb = xyz  + (size_t)b*3*NPTS;
    const float* fb = feat + (size_t)b*3*NPTS;
    float u[6];
    u[0] = __fsub_rn(xb[n],        newxyz[(size_t)bs*3]);
    u[1] = __fsub_rn(xb[NPTS+n],   newxyz[(size_t)bs*3+1]);
    u[2] = __fsub_rn(xb[2*NPTS+n], newxyz[(size_t)bs*3+2]);
    u[3] = fb[n];
    u[4] = fb[NPTS+n];
    u[5] = fb[2*NPTS+n];
    int k = 0;
    #pragma unroll
    for (int i = 0; i < 6; ++i) {
      S[i] += u[i];
      #pragma unroll
      for (int j = i; j < 6; ++j) { Mm[k] = fmaf(u[i], u[j], Mm[k]); ++k; }
    }
  }
  const int lane = t & 63;
  float* dst = accum + (size_t)(blockIdx.x & (NBUCK-1))*32;   // 27 used of 32
  #pragma unroll
  for (int i = 0; i < 6; ++i) {
    float s = add64_dpp(S[i]);
    if (lane == 63) atomicAdd(&dst[i], s);
  }
  #pragma unroll
  for (int k = 0; k < 21; ++k) {
    float m = add64_dpp(Mm[k]);
    if (lane == 63) atomicAdd(&dst[6+k], m);
  }
}

// ---------------- finalize layer-1 BN from moments (closed form) ------------
__global__ void k_finalize1(const float* __restrict__ accum,
                            const float* __restrict__ w0, const float* __restrict__ b0,
                            const float* __restrict__ g, const float* __restrict__ beta,
                            float* __restrict__ scsh) {
  __shared__ float Sm[27];
  const int t = threadIdx.x;
  if (t < 27) {
    float s = 0.f;
    for (int bkt = 0; bkt < NBUCK; ++bkt) s += accum[(size_t)bkt*32 + t];
    Sm[t] = s;
  }
  __syncthreads();
  if (t < 64) {
    const float* w = w0 + t*6;
    const float b = b0[t];
    float ws = 0.f;
    #pragma unroll
    for (int i = 0; i < 6; ++i) ws = fmaf(w[i], Sm[i], ws);
    float quad = 0.f;
    int k = 6;
    #pragma unroll
    for (int i = 0; i < 6; ++i) {
      #pragma unroll
      for (int j = i; j < 6; ++j) {
        float c = w[i]*w[j];
        if (j > i) c *= 2.f;
        quad = fmaf(c, Sm[k], quad);
        ++k;
      }
    }
    const float n = (float)NT_COLS;
    float mean = (ws + n*b) / n;
    float ex2  = (quad + 2.f*b*ws + n*b*b) / n;
    float var  = ex2 - mean*mean;
    if (var < 0.f) var = 0.f;
    float rs = rsqrtf(var + 1e-5f);
    float sc = g[t] * rs;
    scsh[t]    = sc;
    scsh[64+t] = beta[t] - mean * sc;
  }
}

// ---------------- generic bucket finalize (layers 2/3) ----------------------
__global__ void k_finalize(const float* __restrict__ accum,
                           const float* __restrict__ g, const float* __restrict__ beta,
                           float* __restrict__ scsh, int C) {
  int o = threadIdx.x;
  if (o < C) {
    float s = 0.f, ss = 0.f;
    for (int bkt = 0; bkt < NBUCK; ++bkt) {
      s  += accum[(size_t)bkt*(2*C) + o];
      ss += accum[(size_t)bkt*(2*C) + C + o];
    }
    const float n = (float)NT_COLS;
    float mu  = s / n;
    float var = ss / n - mu*mu;
    if (var < 0.f) var = 0.f;
    float rs = rsqrtf(var + 1e-5f);
    float sc = g[o] * rs;
    scsh[o]   = sc;
    scsh[C+o] = beta[o] - mu * sc;
  }
}

#define XT_STRIDE 72   // bf16 elems; 144 B row -> b128-aligned

// ---------------- Layer 2: recompute-x1 staging + MFMA + fused stats --------
__global__ __launch_bounds__(256) void k_layer2_mfma(
    const float* __restrict__ xyz,
    const float* __restrict__ feat,
    const float* __restrict__ newxyz,
    const int*   __restrict__ idx,
    const float* __restrict__ w0g,   // [64][6]
    const float* __restrict__ b0g,   // [64]
    const float* __restrict__ w1,    // [64][64]
    const float* __restrict__ b1,    // [64]
    const float* __restrict__ scsh,  // sc1[64], sh1[64]
    float*       __restrict__ accum, // [NBUCK][128]
    bf16*        __restrict__ x2) {  // [64][NT_COLS]
  __shared__ short xT[256*XT_STRIDE];
  __shared__ float w0s[64*6];
  __shared__ float b0s[64];
  __shared__ float sc_s[64], sh_s[64], bias_s[64];
  const int t = threadIdx.x;
  const int col0 = blockIdx.x * 256;
  for (int i = t; i < 64*6; i += 256) w0s[i] = w0g[i];
  if (t < 64) {
    b0s[t] = b0g[t];
    sc_s[t] = scsh[t]; sh_s[t] = scsh[64+t];
    bias_s[t] = b1[t];
  }
  __syncthreads();
  {
    const int col = col0 + t;
    const int bs = col >> 5;
    const int b  = bs >> 10;
    const int n  = idx[col];
    const float* xb = xyz  + (size_t)b*3*NPTS;
    const float* fb = feat + (size_t)b*3*NPTS;
    float u[6];
    u[0] = __fsub_rn(xb[n],        newxyz[(size_t)bs*3]);
    u[1] = __fsub_rn(xb[NPTS+n],   newxyz[(size_t)bs*3+1]);
    u[2] = __fsub_rn(xb[2*NPTS+n], newxyz[(size_t)bs*3+2]);
    u[3] = fb[n];
    u[4] = fb[NPTS+n];
    u[5] = fb[2*NPTS+n];
    #pragma unroll
    for (int c0 = 0; c0 < 64; c0 += 8) {
      short8 pk;
      #pragma unroll
      for (int j = 0; j < 8; ++j) {
        const int o = c0 + j;
        float v = b0s[o];
        #pragma unroll
        for (int c = 0; c < 6; ++c) v = fmaf(u[c], w0s[o*6+c], v);
        v = fmaxf(fmaf(v, sc_s[o], sh_s[o]), 0.f);   // BN1 + ReLU
        pk[j] = (short)f2bf_bits(v);
      }
      *((short8*)&xT[t*XT_STRIDE + c0]) = pk;
    }
  }
  __syncthreads();
  const int lane = t & 63, wv = t >> 6;
  const int qd = lane >> 4, ln = lane & 15;
  short8 A[4][2];
  #pragma unroll
  for (int rt = 0; rt < 4; ++rt) {
    #pragma unroll
    for (int kh = 0; kh < 2; ++kh) {
      const float* wp = w1 + (size_t)(rt*16 + ln)*64 + kh*32 + qd*8;
      float4 f0 = *(const float4*)wp;
      float4 f1 = *(const float4*)(wp + 4);
      short8 a;
      a[0]=(short)f2bf_bits(f0.x); a[1]=(short)f2bf_bits(f0.y);
      a[2]=(short)f2bf_bits(f0.z); a[3]=(short)f2bf_bits(f0.w);
      a[4]=(short)f2bf_bits(f1.x); a[5]=(short)f2bf_bits(f1.y);
      a[6]=(short)f2bf_bits(f1.z); a[7]=(short)f2bf_bits(f1.w);
      A[rt][kh] = a;
    }
  }
  floatx4 acc[4][4];
  #pragma unroll
  for (int rt = 0; rt < 4; ++rt)
    #pragma unroll
    for (int ct = 0; ct < 4; ++ct)
      acc[rt][ct] = (floatx4)0.f;
  #pragma unroll
  for (int ct = 0; ct < 4; ++ct) {
    const int coll = wv*64 + ct*16 + ln;
    short8 B0 = *((const short8*)&xT[coll*XT_STRIDE + qd*8]);
    short8 B1 = *((const short8*)&xT[coll*XT_STRIDE + 32 + qd*8]);
    #pragma unroll
    for (int rt = 0; rt < 4; ++rt) {
      acc[rt][ct] = __builtin_amdgcn_mfma_f32_16x16x32_bf16(A[rt][0], B0, acc[rt][ct], 0,0,0);
      acc[rt][ct] = __builtin_amdgcn_mfma_f32_16x16x32_bf16(A[rt][1], B1, acc[rt][ct], 0,0,0);
    }
  }
  float* dst = accum + (size_t)(blockIdx.x & (NBUCK-1))*128;
  #pragma unroll
  for (int rt = 0; rt < 4; ++rt) {
    float s[4]  = {0.f,0.f,0.f,0.f};
    float sq[4] = {0.f,0.f,0.f,0.f};
    #pragma unroll
    for (int ct = 0; ct < 4; ++ct) {
      const int col = col0 + wv*64 + ct*16 + ln;
      #pragma unroll
      for (int r = 0; r < 4; ++r) {
        const int o = rt*16 + qd*4 + r;
        float v = acc[rt][ct][r] + bias_s[o];
        x2[(size_t)o*NT_COLS + col] = __float2bfloat16(v);
        s[r] += v; sq[r] = fmaf(v, v, sq[r]);
      }
    }
    #pragma unroll
    for (int r = 0; r < 4; ++r) {
      float a = add16_dpp(s[r]);
      float q = add16_dpp(sq[r]);
      if (ln == 15) {
        const int o = rt*16 + qd*4 + r;
        atomicAdd(&dst[o], a);
        atomicAdd(&dst[64 + o], q);
      }
    }
  }
}

// ---------------- Layer 3: MFMA + fused stats + fused max-pool --------------
__global__ __launch_bounds__(256) void k_layer3_mfma(
    const bf16*  __restrict__ xin,   // [64][NT_COLS] = x2
    const float* __restrict__ wN,    // [128][64]
    const float* __restrict__ bN,    // [128]
    const float* __restrict__ scsh,  // sc2[64], sh2[64]
    float*       __restrict__ accum, // [NBUCK][256]
    float*       __restrict__ mx) {  // [128][NT_COLS/NK]
  constexpr int CO = 128, RT = CO/16;
  __shared__ short xT[256*XT_STRIDE];
  __shared__ float sc_s[64], sh_s[64], bias_s[CO];
  const int t = threadIdx.x;
  const int col0 = blockIdx.x * 256;
  if (t < 64) { sc_s[t] = scsh[t]; sh_s[t] = scsh[64+t]; }
  if (t < CO) bias_s[t] = bN[t];
  __syncthreads();
  {
    const int col = col0 + t;
    #pragma unroll
    for (int c0 = 0; c0 < 64; c0 += 8) {
      short8 pk;
      #pragma unroll
      for (int j = 0; j < 8; ++j) {
        float v = __bfloat162float(xin[(size_t)(c0+j)*NT_COLS + col]);
        v = fmaxf(fmaf(v, sc_s[c0+j], sh_s[c0+j]), 0.f);
        pk[j] = (short)f2bf_bits(v);
      }
      *((short8*)&xT[t*XT_STRIDE + c0]) = pk;
    }
  }
  __syncthreads();
  const int lane = t & 63, wv = t >> 6;
  const int qd = lane >> 4, ln = lane & 15;
  short8 A[RT][2];
  #pragma unroll
  for (int rt = 0; rt < RT; ++rt) {
    #pragma unroll
    for (int kh = 0; kh < 2; ++kh) {
      const float* wp = wN + (size_t)(rt*16 + ln)*64 + kh*32 + qd*8;
      float4 f0 = *(const float4*)wp;
      float4 f1 = *(const float4*)(wp + 4);
      short8 a;
      a[0]=(short)f2bf_bits(f0.x); a[1]=(short)f2bf_bits(f0.y);
      a[2]=(short)f2bf_bits(f0.z); a[3]=(short)f2bf_bits(f0.w);
      a[4]=(short)f2bf_bits(f1.x); a[5]=(short)f2bf_bits(f1.y);
      a[6]=(short)f2bf_bits(f1.z); a[7]=(short)f2bf_bits(f1.w);
      A[rt][kh] = a;
    }
  }
  floatx4 acc[RT][4];
  #pragma unroll
  for (int rt = 0; rt < RT; ++rt)
    #pragma unroll
    for (int ct = 0; ct < 4; ++ct)
      acc[rt][ct] = (floatx4)0.f;
  #pragma unroll
  for (int ct = 0; ct < 4; ++ct) {
    const int coll = wv*64 + ct*16 + ln;
    short8 B0 = *((const short8*)&xT[coll*XT_STRIDE + qd*8]);
    short8 B1 = *((const short8*)&xT[coll*XT_STRIDE + 32 + qd*8]);
    #pragma unroll
    for (int rt = 0; rt < RT; ++rt) {
      acc[rt][ct] = __builtin_amdgcn_mfma_f32_16x16x32_bf16(A[rt][0], B0, acc[rt][ct], 0,0,0);
      acc[rt][ct] = __builtin_amdgcn_mfma_f32_16x16x32_bf16(A[rt][1], B1, acc[rt][ct], 0,0,0);
    }
  }
  float* dst = accum + (size_t)(blockIdx.x & (NBUCK-1))*(2*CO);
  const int bs0 = (col0 + wv*64) >> 5;     // wave covers bs0, bs0+1
  #pragma unroll
  for (int rt = 0; rt < RT; ++rt) {
    float s[4]  = {0.f,0.f,0.f,0.f};
    float sq[4] = {0.f,0.f,0.f,0.f};
    float mxv[2][4];
    #pragma unroll
    for (int h = 0; h < 2; ++h)
      #pragma unroll
      for (int r = 0; r < 4; ++r) mxv[h][r] = -3.402823466e38f;
    #pragma unroll
    for (int ct = 0; ct < 4; ++ct) {
      #pragma unroll
      for (int r = 0; r < 4; ++r) {
        const int o = rt*16 + qd*4 + r;
        float v = acc[rt][ct][r] + bias_s[o];
        mxv[ct>>1][r] = fmaxf(mxv[ct>>1][r], v);
        s[r] += v; sq[r] = fmaf(v, v, sq[r]);
      }
    }
    #pragma unroll
    for (int h = 0; h < 2; ++h) {
      #pragma unroll
      for (int r = 0; r < 4; ++r) {
        float m = mxv[h][r];
        m = fmax_dpp<0x111,0xF,0xF>(m);
        m = fmax_dpp<0x112,0xF,0xF>(m);
        m = fmax_dpp<0x114,0xF,0xF>(m);
        m = fmax_dpp<0x118,0xF,0xF>(m);
        if (ln == 15) {
          const int o = rt*16 + qd*4 + r;
          mx[(size_t)o*(NT_COLS/NK) + bs0 + h] = m;
        }
      }
    }
    #pragma unroll
    for (int r = 0; r < 4; ++r) {
      float a = add16_dpp(s[r]);
      float q = add16_dpp(sq[r]);
      if (ln == 15) {
        const int o = rt*16 + qd*4 + r;
        atomicAdd(&dst[o], a);
        atomicAdd(&dst[CO + o], q);
      }
    }
  }
}

// ---------------- final BN+ReLU on pooled maxes (fp32 out) ------------------
__global__ __launch_bounds__(256) void k_bnmax(const float* __restrict__ mx,
                                               const float* __restrict__ scsh,
                                               float* __restrict__ out1) {
  const int blk = blockIdx.x;        // 16 b x 128 o
  const int o = blk & 127;
  const int b = blk >> 7;
  const float sc = scsh[o], sh = scsh[128+o];
  const int s = threadIdx.x * 4;
  float4 v = *(const float4*)(mx + (size_t)o*(NT_COLS/NK) + b*NS + s);
  float4 r;
  r.x = fmaxf(fmaf(v.x, sc, sh), 0.f);
  r.y = fmaxf(fmaf(v.y, sc, sh), 0.f);
  r.z = fmaxf(fmaf(v.z, sc, sh), 0.f);
  r.w = fmaxf(fmaf(v.w, sc, sh), 0.f);
  *(float4*)(out1 + (size_t)(b*128 + o)*NS + s) = r;
}

extern "C" void kernel_launch(void* const* d_in, const int* in_sizes, int n_in,
                              void* d_out, int out_size, void* d_ws, size_t ws_size,
                              hipStream_t stream) {
  const float* xyz  = (const float*)d_in[0];
  const float* feat = (const float*)d_in[1];
  const float* w0 = (const float*)d_in[2];
  const float* b0 = (const float*)d_in[3];
  const float* g0 = (const float*)d_in[4];
  const float* bt0= (const float*)d_in[5];
  const float* w1 = (const float*)d_in[6];
  const float* b1 = (const float*)d_in[7];
  const float* g1 = (const float*)d_in[8];
  const float* bt1= (const float*)d_in[9];
  const float* w2 = (const float*)d_in[10];
  const float* b2 = (const float*)d_in[11];
  const float* g2 = (const float*)d_in[12];
  const float* bt2= (const float*)d_in[13];

  float* out0 = (float*)d_out;                     // (B,3,NS) fp32
  float* out1 = out0 + (size_t)NB*3*NS;            // (B,128,NS) fp32

  // Workspace (max offset ~138 MB; ws >= 194 MB proven):
  //   accum@0 (128KB, zeroed by k_fps prologue), scsh@131072,
  //   newxyz@133120, bidx@329728, x2@2426880 (64MB), mx3@136644608 (8MB)
  char* ws = (char*)d_ws;
  float* accum  = (float*)(ws + 0);
  float* acc_l1 = accum;                 // NBUCK x 32 (27 used: S6 + M21)
  float* acc_l2 = accum + 8192;          // NBUCK x 128
  float* acc_l3 = accum + 16384;         // NBUCK x 256
  float* scsh   = (float*)(ws + 131072);
  float* newxyz = (float*)(ws + 133120);
  int*   bidx   = (int*)  (ws + 329728);
  bf16*  x2     = (bf16*) (ws + 2426880);
  float* mx3    = (float*)(ws + 136644608);

  k_fps  <<<NB, 256, 0, stream>>>(xyz, newxyz, out0, accum);
  k_ballq<<<NB*256, 256, 0, stream>>>(xyz, newxyz, bidx);

  k_moments  <<<256, 256, 0, stream>>>(xyz, feat, newxyz, bidx, acc_l1);
  k_finalize1<<<1,    64, 0, stream>>>(acc_l1, w0, b0, g0, bt0, scsh + 0);

  k_layer2_mfma<<<NT_COLS/256, 256, 0, stream>>>(xyz, feat, newxyz, bidx,
                                                 w0, b0, w1, b1, scsh + 0,
                                                 acc_l2, x2);
  k_finalize<<<1, 256, 0, stream>>>(acc_l2, g1, bt1, scsh + 128, 64);

  k_layer3_mfma<<<NT_COLS/256, 256, 0, stream>>>(x2, w2, b2, scsh + 128,
                                                 acc_l3, mx3);
  k_finalize<<<1, 256, 0, stream>>>(acc_l3, g2, bt2, scsh + 256, 128);

  k_bnmax <<<NB*128, 256, 0, stream>>>(mx3, scsh + 256, out1);
}